// Round 8
// baseline (518.018 us; speedup 1.0000x reference)
//
#include <hip/hip_runtime.h>
#include <cstdint>
#include <cstddef>

#define T 4096
#define C 768
#define HD 64
#define NH 12

typedef float f32x4 __attribute__((ext_vector_type(4)));
typedef __bf16 bf16x8 __attribute__((ext_vector_type(8)));
typedef short s16x4 __attribute__((ext_vector_type(4)));
typedef unsigned short u16;

static __device__ __forceinline__ u16 f2bf(float f) {
    union { __bf16 h; u16 u; } cv;
    cv.h = (__bf16)f;
    return cv.u;
}

static __device__ __forceinline__ float exp2_hw(float x) {
    float r;
    asm("v_exp_f32 %0, %1" : "=v"(r) : "v"(x));
    return r;
}

static __device__ __forceinline__ void load_lds16(const void* g, void* l) {
    __builtin_amdgcn_global_load_lds(
        (const __attribute__((address_space(1))) void*)g,
        (__attribute__((address_space(3))) void*)l, 16, 0, 0);
}

// D = A(16x16)*B(16x16)+D, bf16 K=16; A/B: 4 bf16/lane, k = quad*4 + j.
static __device__ __forceinline__ void mfma16(f32x4& acc, s16x4 a, s16x4 b) {
#if defined(__HIP_DEVICE_COMPILE__)
#if __has_builtin(__builtin_amdgcn_mfma_f32_16x16x16bf16_1k)
    acc = __builtin_amdgcn_mfma_f32_16x16x16bf16_1k(a, b, acc, 0, 0, 0);
#else
    asm volatile("s_nop 2\n\t"
                 "v_mfma_f32_16x16x16_bf16 %0, %1, %2, %0\n\t"
                 "s_nop 7\n\t"
                 "s_nop 7"
                 : "+v"(acc) : "v"(a), "v"(b));
#endif
#else
    (void)acc; (void)a; (void)b;
#endif
}

// ---------------------------------------------------------------- convert (all inputs, one launch)
__global__ __launch_bounds__(256) void cvt_all(
    const float* __restrict__ hs, const float* __restrict__ w0,
    const float* __restrict__ w1, const float* __restrict__ w2,
    const float* __restrict__ w3, const float* __restrict__ rh,
    const float* __restrict__ rw,
    u16* __restrict__ dhs, u16* __restrict__ dw0, u16* __restrict__ dw1,
    u16* __restrict__ dw2, u16* __restrict__ dw3, u16* __restrict__ drh,
    u16* __restrict__ drw) {
    const int NHS = T * C;
    const int NW = C * C;
    const int NR = 127 * HD;
    const int NTOT = NHS + 4 * NW + 2 * NR;
    int i = (blockIdx.x * 256 + threadIdx.x) * 4;
    if (i >= NTOT) return;
    const float* s; u16* d; int j;
    if (i < NHS) { s = hs; d = dhs; j = i; }
    else if (i < NHS + 4 * NW) {
        j = i - NHS;
        int t = j / NW; j -= t * NW;
        s = (t == 0) ? w0 : (t == 1) ? w1 : (t == 2) ? w2 : w3;
        d = (t == 0) ? dw0 : (t == 1) ? dw1 : (t == 2) ? dw2 : dw3;
    } else {
        j = i - NHS - 4 * NW;
        if (j < NR) { s = rh; d = drh; }
        else { s = rw; d = drw; j -= NR; }
    }
    float4 v = *(const float4*)(s + j);
    d[j + 0] = f2bf(v.x);
    d[j + 1] = f2bf(v.y);
    d[j + 2] = f2bf(v.z);
    d[j + 3] = f2bf(v.w);
}

// ---------------------------------------------------------------- QKV GEMM (unchanged from R7)
__global__ __launch_bounds__(256, 2) void gemm_qkv_kernel(
    const u16* __restrict__ xb,
    const u16* __restrict__ wq, const u16* __restrict__ wk, const u16* __restrict__ wv,
    const float* __restrict__ qb, const float* __restrict__ kb, const float* __restrict__ vb,
    u16* __restrict__ Q, u16* __restrict__ K, u16* __restrict__ V) {
    __shared__ __align__(16) u16 As[2][128 * 64];
    __shared__ __align__(16) u16 Bs[2][128 * 64];
    const int z = blockIdx.z;
    const u16* W = (z == 0) ? wq : (z == 1) ? wk : wv;
    const float* bias = (z == 0) ? qb : (z == 1) ? kb : vb;
    u16* dst = (z == 0) ? Q : (z == 1) ? K : V;
    const int m0 = blockIdx.x * 128, n0 = blockIdx.y * 128;
    const int tid = threadIdx.x;
    const int wave = tid >> 6, lane = tid & 63, quad = lane >> 4, l15 = lane & 15;
    const int r0 = (wave >> 1) * 64, c0 = (wave & 1) * 64;
    int srow[4], sx[4], sdst[4];
#pragma unroll
    for (int i = 0; i < 4; ++i) {
        int p = i * 256 + wave * 64 + lane;
        srow[i] = p >> 3;
        sx[i] = (p & 7) ^ (srow[i] & 7);
        sdst[i] = (i * 256 + wave * 64) * 8;
    }
    f32x4 acc[4][4] = {};
#pragma unroll
    for (int i = 0; i < 4; ++i) {
        load_lds16(xb + (size_t)(m0 + srow[i]) * C + sx[i] * 8, &As[0][sdst[i]]);
        load_lds16(W + (size_t)(n0 + srow[i]) * C + sx[i] * 8, &Bs[0][sdst[i]]);
    }
    for (int kt = 0; kt < 12; ++kt) {
        const int cur = kt & 1;
        __syncthreads();
        if (kt < 11) {
            const int k0 = (kt + 1) * 64;
#pragma unroll
            for (int i = 0; i < 4; ++i) {
                load_lds16(xb + (size_t)(m0 + srow[i]) * C + k0 + sx[i] * 8, &As[cur ^ 1][sdst[i]]);
                load_lds16(W + (size_t)(n0 + srow[i]) * C + k0 + sx[i] * 8, &Bs[cur ^ 1][sdst[i]]);
            }
        }
#pragma unroll
        for (int kk = 0; kk < 2; ++kk) {
            bf16x8 af[4], bfr[4];
#pragma unroll
            for (int mi = 0; mi < 4; ++mi) {
                int r = r0 + mi * 16 + l15;
                af[mi] = *(const bf16x8*)&As[cur][r * 64 + (((kk * 4 + quad) ^ (r & 7)) * 8)];
            }
#pragma unroll
            for (int ni = 0; ni < 4; ++ni) {
                int r = c0 + ni * 16 + l15;
                bfr[ni] = *(const bf16x8*)&Bs[cur][r * 64 + (((kk * 4 + quad) ^ (r & 7)) * 8)];
            }
#pragma unroll
            for (int mi = 0; mi < 4; ++mi)
#pragma unroll
                for (int ni = 0; ni < 4; ++ni)
                    acc[mi][ni] = __builtin_amdgcn_mfma_f32_16x16x32_bf16(af[mi], bfr[ni], acc[mi][ni], 0, 0, 0);
        }
    }
#pragma unroll
    for (int mi = 0; mi < 4; ++mi)
#pragma unroll
        for (int ni = 0; ni < 4; ++ni)
#pragma unroll
            for (int r = 0; r < 4; ++r) {
                int m = m0 + r0 + mi * 16 + quad * 4 + r;
                int n = n0 + c0 + ni * 16 + l15;
                float v = acc[mi][ni][r] + bias[n];
                dst[(size_t)(n >> 6) * T * HD + (size_t)m * HD + (n & 63)] = f2bf(v);
            }
}

// ---------------------------------------------------------------- proj GEMM (unchanged)
__global__ __launch_bounds__(256, 2) void gemm_proj_kernel(
    const u16* __restrict__ A, const u16* __restrict__ W,
    const float* __restrict__ bias, float* __restrict__ out) {
    __shared__ __align__(16) u16 As[2][128 * 64];
    __shared__ __align__(16) u16 Bs[2][128 * 64];
    const int m0 = blockIdx.x * 128, n0 = blockIdx.y * 128;
    const int tid = threadIdx.x;
    const int wave = tid >> 6, lane = tid & 63, quad = lane >> 4, l15 = lane & 15;
    const int r0 = (wave >> 1) * 64, c0 = (wave & 1) * 64;
    int srow[4], sx[4], sdst[4];
#pragma unroll
    for (int i = 0; i < 4; ++i) {
        int p = i * 256 + wave * 64 + lane;
        srow[i] = p >> 3;
        sx[i] = (p & 7) ^ (srow[i] & 7);
        sdst[i] = (i * 256 + wave * 64) * 8;
    }
    f32x4 acc[4][4] = {};
#pragma unroll
    for (int i = 0; i < 4; ++i) {
        load_lds16(A + (size_t)(m0 + srow[i]) * C + sx[i] * 8, &As[0][sdst[i]]);
        load_lds16(W + (size_t)(n0 + srow[i]) * C + sx[i] * 8, &Bs[0][sdst[i]]);
    }
    for (int kt = 0; kt < 12; ++kt) {
        const int cur = kt & 1;
        __syncthreads();
        if (kt < 11) {
            const int k0 = (kt + 1) * 64;
#pragma unroll
            for (int i = 0; i < 4; ++i) {
                load_lds16(A + (size_t)(m0 + srow[i]) * C + k0 + sx[i] * 8, &As[cur ^ 1][sdst[i]]);
                load_lds16(W + (size_t)(n0 + srow[i]) * C + k0 + sx[i] * 8, &Bs[cur ^ 1][sdst[i]]);
            }
        }
#pragma unroll
        for (int kk = 0; kk < 2; ++kk) {
            bf16x8 af[4], bfr[4];
#pragma unroll
            for (int mi = 0; mi < 4; ++mi) {
                int r = r0 + mi * 16 + l15;
                af[mi] = *(const bf16x8*)&As[cur][r * 64 + (((kk * 4 + quad) ^ (r & 7)) * 8)];
            }
#pragma unroll
            for (int ni = 0; ni < 4; ++ni) {
                int r = c0 + ni * 16 + l15;
                bfr[ni] = *(const bf16x8*)&Bs[cur][r * 64 + (((kk * 4 + quad) ^ (r & 7)) * 8)];
            }
#pragma unroll
            for (int mi = 0; mi < 4; ++mi)
#pragma unroll
                for (int ni = 0; ni < 4; ++ni)
                    acc[mi][ni] = __builtin_amdgcn_mfma_f32_16x16x32_bf16(af[mi], bfr[ni], acc[mi][ni], 0, 0, 0);
        }
    }
#pragma unroll
    for (int mi = 0; mi < 4; ++mi)
#pragma unroll
        for (int ni = 0; ni < 4; ++ni)
#pragma unroll
            for (int r = 0; r < 4; ++r) {
                int m = m0 + r0 + mi * 16 + quad * 4 + r;
                int n = n0 + c0 + ni * 16 + l15;
                out[(size_t)m * C + n] = acc[mi][ni][r] + bias[n];
            }
}

// ---------------------------------------------------------------- V transpose (unchanged)
__global__ __launch_bounds__(256) void vtrans_kernel(const u16* __restrict__ V,
                                                     u16* __restrict__ Vt) {
    __shared__ __align__(16) u16 tl[64 * 72];
    const int h = blockIdx.y, t0 = blockIdx.x * 64, tid = threadIdx.x;
#pragma unroll
    for (int i = 0; i < 2; ++i) {
        int c = i * 256 + tid;
        int row = c >> 3, col = (c & 7) * 8;
        union { float4 f; u16 u[8]; } cv;
        cv.f = *(const float4*)(V + (size_t)h * T * HD + (size_t)(t0 + row) * HD + col);
#pragma unroll
        for (int j = 0; j < 8; ++j) tl[(col + j) * 72 + row] = cv.u[j];
    }
    __syncthreads();
#pragma unroll
    for (int i = 0; i < 2; ++i) {
        int c = i * 256 + tid;
        int drow = c >> 3, tcol = (c & 7) * 8;
        float4 v = *(const float4*)&tl[drow * 72 + tcol];
        *(float4*)(Vt + (size_t)(h * HD + drow) * T + t0 + tcol) = v;
    }
}

// ---------------------------------------------------------------- rel_h (unchanged)
__global__ __launch_bounds__(256) void relh_kernel(const u16* __restrict__ Q,
                                                   const u16* __restrict__ rph,
                                                   float* __restrict__ relH) {
    const float LOG2E = 1.4426950408889634f;
    const int hq = blockIdx.x, h = blockIdx.y;
    const int tid = threadIdx.x, wave = tid >> 6, lane = tid & 63;
    const int quad = lane >> 4, l15 = lane & 15;
    f32x4 acc[4] = {};
    bf16x8 a[2], b[4][2];
#pragma unroll
    for (int kk = 0; kk < 2; ++kk) {
        int hk = wave * 16 + l15;
        a[kk] = *(const bf16x8*)(rph + (size_t)(hq - hk + 63) * HD + kk * 32 + quad * 8);
    }
#pragma unroll
    for (int nt = 0; nt < 4; ++nt)
#pragma unroll
        for (int kk = 0; kk < 2; ++kk)
            b[nt][kk] = *(const bf16x8*)(Q + (size_t)h * T * HD +
                                         (size_t)(hq * 64 + nt * 16 + l15) * HD + kk * 32 + quad * 8);
#pragma unroll
    for (int nt = 0; nt < 4; ++nt) {
        acc[nt] = __builtin_amdgcn_mfma_f32_16x16x32_bf16(a[0], b[nt][0], acc[nt], 0, 0, 0);
        acc[nt] = __builtin_amdgcn_mfma_f32_16x16x32_bf16(a[1], b[nt][1], acc[nt], 0, 0, 0);
    }
#pragma unroll
    for (int nt = 0; nt < 4; ++nt) {
        float4 v;
        v.x = acc[nt][0] * LOG2E; v.y = acc[nt][1] * LOG2E;
        v.z = acc[nt][2] * LOG2E; v.w = acc[nt][3] * LOG2E;
        *(float4*)(relH + (((size_t)(h * 64 + hq) * 64 + nt * 16 + l15) * 64) +
                   wave * 16 + quad * 4) = v;
    }
}

// ---------------------------------------------------------------- rel_w (unchanged)
__global__ __launch_bounds__(256) void relw_kernel(const u16* __restrict__ Q,
                                                   const u16* __restrict__ rpw,
                                                   float* __restrict__ relW) {
    const float LOG2E = 1.4426950408889634f;
    const int wq = blockIdx.x, h = blockIdx.y;
    const int tid = threadIdx.x, wave = tid >> 6, lane = tid & 63;
    const int quad = lane >> 4, l15 = lane & 15;
    f32x4 acc[4] = {};
    bf16x8 a[2], b[4][2];
#pragma unroll
    for (int kk = 0; kk < 2; ++kk) {
        int hqr = wave * 16 + l15;
        a[kk] = *(const bf16x8*)(Q + (size_t)h * T * HD +
                                 (size_t)(hqr * 64 + wq) * HD + kk * 32 + quad * 8);
    }
#pragma unroll
    for (int nt = 0; nt < 4; ++nt)
#pragma unroll
        for (int kk = 0; kk < 2; ++kk) {
            int wk = nt * 16 + l15;
            b[nt][kk] = *(const bf16x8*)(rpw + (size_t)(wq - wk + 63) * HD + kk * 32 + quad * 8);
        }
#pragma unroll
    for (int nt = 0; nt < 4; ++nt) {
        acc[nt] = __builtin_amdgcn_mfma_f32_16x16x32_bf16(a[0], b[nt][0], acc[nt], 0, 0, 0);
        acc[nt] = __builtin_amdgcn_mfma_f32_16x16x32_bf16(a[1], b[nt][1], acc[nt], 0, 0, 0);
    }
#pragma unroll
    for (int nt = 0; nt < 4; ++nt)
#pragma unroll
        for (int r = 0; r < 4; ++r) {
            int hqr = wave * 16 + quad * 4 + r;
            relW[((size_t)h * T + hqr * 64 + wq) * 64 + nt * 16 + l15] = acc[nt][r] * LOG2E;
        }
}

// ---------------------------------------------------------------- flash attention (key-split waves)
// block = 64 q (one hq row); wave w owns keys w*16..+15 of EVERY tile x all 64 q
// (4 q-bands). LDS reads/iter/wave: 2 b128 (K) + 4 b64 (V) — 4x less than q-split.
// No-max softmax => partial O / rowsums over disjoint key sets are additive;
// one LDS combine at the end.
__global__ __launch_bounds__(256, 3) void attn_kernel(
    const u16* __restrict__ Q, const u16* __restrict__ K, const u16* __restrict__ Vt,
    const float* __restrict__ relH, const float* __restrict__ relW,
    u16* __restrict__ AO) {
    // 0..16383: kbuf[2][4096] u16 | 16384..32767: vbuf[2][4096] u16
    // epilogue: fs f32[4][64][44] (0..45055) | rs f32[4][64] (45056..46079)
    __shared__ __align__(16) unsigned char smem[46080];
    u16* kb = (u16*)smem;
    u16* vb = (u16*)(smem + 16384);
    float* fs = (float*)smem;
    float* rs = (float*)(smem + 45056);

    const int hq = blockIdx.x, h = blockIdx.y;
    const int t0 = hq * 64;
    const int tid = threadIdx.x, w = tid >> 6, lane = tid & 63;
    const int quad = lane >> 4, l15 = lane & 15;
    const float C1 = 0.18033688011112042f;   // 0.125 * log2(e)

    const u16* Kbase = K + (size_t)h * T * HD;
    const u16* Vbase = Vt + (size_t)h * HD * T;

    // staging geometry (512 x 16B chunks per tile; 2 per thread) — as R7
    const int p0 = w * 128 + lane, p1 = p0 + 64;
    const int sr0 = p0 >> 3, sx0 = (p0 & 7) ^ (sr0 & 7);
    const int sr1 = p1 >> 3, sx1 = (p1 & 7) ^ (sr1 & 7);
    const int lds0 = w * 1024, lds1 = w * 1024 + 512;

    // Q B-fragments for 4 q-bands (q = band*16 + l15)
    bf16x8 qa[4][2];
#pragma unroll
    for (int band = 0; band < 4; ++band)
#pragma unroll
        for (int kk = 0; kk < 2; ++kk)
            qa[band][kk] = *(const bf16x8*)(Q + (size_t)h * T * HD +
                                            (size_t)(t0 + band * 16 + l15) * HD + kk * 32 + quad * 8);
    // rel_w (pre-scaled): element (key w*16+quad*4+r, q band*16+l15) needs wk = w*16+quad*4+r
    f32x4 rw4[4];
#pragma unroll
    for (int band = 0; band < 4; ++band)
        rw4[band] = *(const f32x4*)(relW + ((size_t)h * T + t0 + band * 16 + l15) * 64 +
                                    w * 16 + quad * 4);
    // rel_h (pre-scaled): [h][hq][q][hk], hk contiguous
    const float* rhB = relH + ((size_t)(h * 64 + hq) * 64 + l15) * 64;

    f32x4 oa[4][4] = {};          // [band][dg]
    float lsum[4] = {0.f, 0.f, 0.f, 0.f};

    // prologue: stage tile 0
    load_lds16(Kbase + sr0 * HD + sx0 * 8, &kb[lds0]);
    load_lds16(Kbase + sr1 * HD + sx1 * 8, &kb[lds1]);
    load_lds16(Vbase + (size_t)sr0 * T + sx0 * 8, &vb[lds0]);
    load_lds16(Vbase + (size_t)sr1 * T + sx1 * 8, &vb[lds1]);

    for (int hk4 = 0; hk4 < 16; ++hk4) {
        f32x4 rh4[4];
#pragma unroll
        for (int band = 0; band < 4; ++band)
            rh4[band] = *(const f32x4*)(rhB + band * 1024 + hk4 * 4);
#pragma unroll
        for (int rr = 0; rr < 4; ++rr) {
            const int hk = hk4 * 4 + rr;
            const int cur = rr & 1;
            __syncthreads();
            if (hk < 63) {
                const int tk0 = (hk + 1) * 64;
                load_lds16(Kbase + (size_t)(tk0 + sr0) * HD + sx0 * 8, &kb[(cur ^ 1) * 4096 + lds0]);
                load_lds16(Kbase + (size_t)(tk0 + sr1) * HD + sx1 * 8, &kb[(cur ^ 1) * 4096 + lds1]);
                load_lds16(Vbase + (size_t)sr0 * T + tk0 + sx0 * 8, &vb[(cur ^ 1) * 4096 + lds0]);
                load_lds16(Vbase + (size_t)sr1 * T + tk0 + sx1 * 8, &vb[(cur ^ 1) * 4096 + lds1]);
            }
            const u16* kc = kb + cur * 4096;
            const u16* vc = vb + cur * 4096;
            // K A-fragments for this wave's 16 keys (rows w*16+l15)
            bf16x8 af0 = *(const bf16x8*)&kc[(w * 16 + l15) * 64 + ((quad ^ (l15 & 7)) * 8)];
            bf16x8 af1 = *(const bf16x8*)&kc[(w * 16 + l15) * 64 + (((4 + quad) ^ (l15 & 7)) * 8)];
            // V^T A-fragments (rows d = dg*16+l15, keys w*16+quad*4..+3)
            s16x4 vf[4];
#pragma unroll
            for (int dg = 0; dg < 4; ++dg)
                vf[dg] = *(const s16x4*)&vc[(dg * 16 + l15) * 64 +
                                            (((w * 2 + (quad >> 1)) ^ (l15 & 7)) * 8) +
                                            (quad & 1) * 4];
#pragma unroll
            for (int band = 0; band < 4; ++band) {
                f32x4 s4 = {};
                s4 = __builtin_amdgcn_mfma_f32_16x16x32_bf16(af0, qa[band][0], s4, 0, 0, 0);
                s4 = __builtin_amdgcn_mfma_f32_16x16x32_bf16(af1, qa[band][1], s4, 0, 0, 0);
                const float rhc = rh4[band][rr];
                float e0 = exp2_hw(s4[0] * C1 + rhc + rw4[band][0]);
                float e1 = exp2_hw(s4[1] * C1 + rhc + rw4[band][1]);
                float e2 = exp2_hw(s4[2] * C1 + rhc + rw4[band][2]);
                float e3 = exp2_hw(s4[3] * C1 + rhc + rw4[band][3]);
                lsum[band] += (e0 + e1) + (e2 + e3);
                s16x4 pB;
                pB[0] = (short)f2bf(e0); pB[1] = (short)f2bf(e1);
                pB[2] = (short)f2bf(e2); pB[3] = (short)f2bf(e3);
#pragma unroll
                for (int dg = 0; dg < 4; ++dg)
                    mfma16(oa[band][dg], vf[dg], pB);
            }
        }
    }
    // ---- combine across key-quarter waves ----
    __syncthreads();                       // all loop LDS reads complete
#pragma unroll
    for (int band = 0; band < 4; ++band) {
        float t = lsum[band];
        t += __shfl_xor(t, 16);
        t += __shfl_xor(t, 32);            // sum over quads (keys within wave's 16)
        if (quad == 0) rs[w * 64 + band * 16 + l15] = t;
    }
    __syncthreads();
    const int qe = w * 16 + l15;           // epilogue q owned by this lane
    const float inv = 1.0f / (rs[qe] + rs[64 + qe] + rs[128 + qe] + rs[192 + qe]);
#pragma unroll
    for (int half = 0; half < 2; ++half) {
        // write partials: fs[p=w][q][d32], stride 44 (16B-aligned, ≤2-way banks)
#pragma unroll
        for (int band = 0; band < 4; ++band)
#pragma unroll
            for (int dgl = 0; dgl < 2; ++dgl)
                *(f32x4*)&fs[(size_t)(w * 64 + band * 16 + l15) * 44 + dgl * 16 + quad * 4] =
                    oa[band][half * 2 + dgl];
        __syncthreads();
        float o[8] = {};
#pragma unroll
        for (int p = 0; p < 4; ++p)
#pragma unroll
            for (int j = 0; j < 2; ++j) {
                f32x4 t4 = *(const f32x4*)&fs[(size_t)(p * 64 + qe) * 44 + quad * 8 + j * 4];
                o[j * 4 + 0] += t4[0]; o[j * 4 + 1] += t4[1];
                o[j * 4 + 2] += t4[2]; o[j * 4 + 3] += t4[3];
            }
        uint4 st;
        st.x = (unsigned)f2bf(o[0] * inv) | ((unsigned)f2bf(o[1] * inv) << 16);
        st.y = (unsigned)f2bf(o[2] * inv) | ((unsigned)f2bf(o[3] * inv) << 16);
        st.z = (unsigned)f2bf(o[4] * inv) | ((unsigned)f2bf(o[5] * inv) << 16);
        st.w = (unsigned)f2bf(o[6] * inv) | ((unsigned)f2bf(o[7] * inv) << 16);
        *(uint4*)(AO + (size_t)(t0 + qe) * C + h * 64 + half * 32 + quad * 8) = st;
        __syncthreads();                   // reads done before next round's writes
    }
}

// ---------------------------------------------------------------- launch
extern "C" void kernel_launch(void* const* d_in, const int* in_sizes, int n_in,
                              void* d_out, int out_size, void* d_ws, size_t ws_size,
                              hipStream_t stream) {
    (void)in_sizes; (void)n_in; (void)out_size; (void)ws_size;
    const float* hs  = (const float*)d_in[0];
    const float* q_w = (const float*)d_in[1];
    const float* q_b = (const float*)d_in[2];
    const float* k_w = (const float*)d_in[3];
    const float* k_b = (const float*)d_in[4];
    const float* v_w = (const float*)d_in[5];
    const float* v_b = (const float*)d_in[6];
    const float* p_w = (const float*)d_in[7];
    const float* p_b = (const float*)d_in[8];
    const float* rph = (const float*)d_in[9];
    const float* rpw = (const float*)d_in[10];

    char* ws = (char*)d_ws;
    size_t off = 0;
    auto alloc = [&](size_t bytes) {
        void* p = ws + off;
        off = (off + bytes + 255) & ~(size_t)255;
        return p;
    };
    u16* xb   = (u16*)alloc((size_t)T * C * 2);
    u16* wqb  = (u16*)alloc((size_t)C * C * 2);
    u16* wkb  = (u16*)alloc((size_t)C * C * 2);
    u16* wvb  = (u16*)alloc((size_t)C * C * 2);
    u16* wpb  = (u16*)alloc((size_t)C * C * 2);
    u16* rphb = (u16*)alloc((size_t)127 * HD * 2);
    u16* rpwb = (u16*)alloc((size_t)127 * HD * 2);
    u16* Qb   = (u16*)alloc((size_t)NH * T * HD * 2);
    u16* Kb   = (u16*)alloc((size_t)NH * T * HD * 2);
    u16* Vb   = (u16*)alloc((size_t)NH * T * HD * 2);
    u16* Vt   = (u16*)alloc((size_t)NH * T * HD * 2);
    float* relH = (float*)alloc((size_t)NH * T * 64 * 4);
    float* relW = (float*)alloc((size_t)NH * T * 64 * 4);
    u16* AO   = (u16*)alloc((size_t)T * C * 2);

    const int NTOT = T * C + 4 * C * C + 2 * 127 * HD;
    cvt_all<<<dim3((NTOT / 4 + 255) / 256), dim3(256), 0, stream>>>(
        hs, q_w, k_w, v_w, p_w, rph, rpw, xb, wqb, wkb, wvb, wpb, rphb, rpwb);

    gemm_qkv_kernel<<<dim3(32, 6, 3), dim3(256), 0, stream>>>(
        xb, wqb, wkb, wvb, q_b, k_b, v_b, Qb, Kb, Vb);
    vtrans_kernel<<<dim3(64, NH), dim3(256), 0, stream>>>(Vb, Vt);
    relh_kernel<<<dim3(64, NH), dim3(256), 0, stream>>>(Qb, rphb, relH);
    relw_kernel<<<dim3(64, NH), dim3(256), 0, stream>>>(Qb, rpwb, relW);
    attn_kernel<<<dim3(64, NH), dim3(256), 0, stream>>>(Qb, Kb, Vt, relH, relW, AO);
    gemm_proj_kernel<<<dim3(32, 6), dim3(256), 0, stream>>>(AO, wpb, p_b, (float*)d_out);
}

// Round 9
// 233.944 us; speedup vs baseline: 2.2143x; 2.2143x over previous
//
#include <hip/hip_runtime.h>
#include <cstdint>
#include <cstddef>

#define T 4096
#define C 768
#define HD 64
#define NH 12

typedef float f32x4 __attribute__((ext_vector_type(4)));
typedef __bf16 bf16x8 __attribute__((ext_vector_type(8)));
typedef short s16x4 __attribute__((ext_vector_type(4)));
typedef unsigned short u16;

static __device__ __forceinline__ u16 f2bf(float f) {
    union { __bf16 h; u16 u; } cv;
    cv.h = (__bf16)f;
    return cv.u;
}

static __device__ __forceinline__ float exp2_hw(float x) {
    float r;
    asm("v_exp_f32 %0, %1" : "=v"(r) : "v"(x));
    return r;
}

static __device__ __forceinline__ void load_lds16(const void* g, void* l) {
    __builtin_amdgcn_global_load_lds(
        (const __attribute__((address_space(1))) void*)g,
        (__attribute__((address_space(3))) void*)l, 16, 0, 0);
}

// D = A(16x16)*B(16x16)+D, bf16 K=16; A/B: 4 bf16/lane, k = quad*4 + j.
static __device__ __forceinline__ void mfma16(f32x4& acc, s16x4 a, s16x4 b) {
#if defined(__HIP_DEVICE_COMPILE__)
#if __has_builtin(__builtin_amdgcn_mfma_f32_16x16x16bf16_1k)
    acc = __builtin_amdgcn_mfma_f32_16x16x16bf16_1k(a, b, acc, 0, 0, 0);
#else
    asm volatile("s_nop 2\n\t"
                 "v_mfma_f32_16x16x16_bf16 %0, %1, %2, %0\n\t"
                 "s_nop 7\n\t"
                 "s_nop 7"
                 : "+v"(acc) : "v"(a), "v"(b));
#endif
#else
    (void)acc; (void)a; (void)b;
#endif
}

// ---------------------------------------------------------------- convert (all inputs, one launch)
__global__ __launch_bounds__(256) void cvt_all(
    const float* __restrict__ hs, const float* __restrict__ w0,
    const float* __restrict__ w1, const float* __restrict__ w2,
    const float* __restrict__ w3, const float* __restrict__ rh,
    const float* __restrict__ rw,
    u16* __restrict__ dhs, u16* __restrict__ dw0, u16* __restrict__ dw1,
    u16* __restrict__ dw2, u16* __restrict__ dw3, u16* __restrict__ drh,
    u16* __restrict__ drw) {
    const int NHS = T * C;
    const int NW = C * C;
    const int NR = 127 * HD;
    const int NTOT = NHS + 4 * NW + 2 * NR;
    int i = (blockIdx.x * 256 + threadIdx.x) * 4;
    if (i >= NTOT) return;
    const float* s; u16* d; int j;
    if (i < NHS) { s = hs; d = dhs; j = i; }
    else if (i < NHS + 4 * NW) {
        j = i - NHS;
        int t = j / NW; j -= t * NW;
        s = (t == 0) ? w0 : (t == 1) ? w1 : (t == 2) ? w2 : w3;
        d = (t == 0) ? dw0 : (t == 1) ? dw1 : (t == 2) ? dw2 : dw3;
    } else {
        j = i - NHS - 4 * NW;
        if (j < NR) { s = rh; d = drh; }
        else { s = rw; d = drw; j -= NR; }
    }
    float4 v = *(const float4*)(s + j);
    d[j + 0] = f2bf(v.x);
    d[j + 1] = f2bf(v.y);
    d[j + 2] = f2bf(v.z);
    d[j + 3] = f2bf(v.w);
}

// ---------------------------------------------------------------- QKV GEMM
__global__ __launch_bounds__(256, 2) void gemm_qkv_kernel(
    const u16* __restrict__ xb,
    const u16* __restrict__ wq, const u16* __restrict__ wk, const u16* __restrict__ wv,
    const float* __restrict__ qb, const float* __restrict__ kb, const float* __restrict__ vb,
    u16* __restrict__ Q, u16* __restrict__ K, u16* __restrict__ V) {
    __shared__ __align__(16) u16 As[2][128 * 64];
    __shared__ __align__(16) u16 Bs[2][128 * 64];
    const int z = blockIdx.z;
    const u16* W = (z == 0) ? wq : (z == 1) ? wk : wv;
    const float* bias = (z == 0) ? qb : (z == 1) ? kb : vb;
    u16* dst = (z == 0) ? Q : (z == 1) ? K : V;
    const int m0 = blockIdx.x * 128, n0 = blockIdx.y * 128;
    const int tid = threadIdx.x;
    const int wave = tid >> 6, lane = tid & 63, quad = lane >> 4, l15 = lane & 15;
    const int r0 = (wave >> 1) * 64, c0 = (wave & 1) * 64;
    int srow[4], sx[4], sdst[4];
#pragma unroll
    for (int i = 0; i < 4; ++i) {
        int p = i * 256 + wave * 64 + lane;
        srow[i] = p >> 3;
        sx[i] = (p & 7) ^ (srow[i] & 7);
        sdst[i] = (i * 256 + wave * 64) * 8;
    }
    f32x4 acc[4][4] = {};
#pragma unroll
    for (int i = 0; i < 4; ++i) {
        load_lds16(xb + (size_t)(m0 + srow[i]) * C + sx[i] * 8, &As[0][sdst[i]]);
        load_lds16(W + (size_t)(n0 + srow[i]) * C + sx[i] * 8, &Bs[0][sdst[i]]);
    }
    for (int kt = 0; kt < 12; ++kt) {
        const int cur = kt & 1;
        __syncthreads();
        if (kt < 11) {
            const int k0 = (kt + 1) * 64;
#pragma unroll
            for (int i = 0; i < 4; ++i) {
                load_lds16(xb + (size_t)(m0 + srow[i]) * C + k0 + sx[i] * 8, &As[cur ^ 1][sdst[i]]);
                load_lds16(W + (size_t)(n0 + srow[i]) * C + k0 + sx[i] * 8, &Bs[cur ^ 1][sdst[i]]);
            }
        }
#pragma unroll
        for (int kk = 0; kk < 2; ++kk) {
            bf16x8 af[4], bfr[4];
#pragma unroll
            for (int mi = 0; mi < 4; ++mi) {
                int r = r0 + mi * 16 + l15;
                af[mi] = *(const bf16x8*)&As[cur][r * 64 + (((kk * 4 + quad) ^ (r & 7)) * 8)];
            }
#pragma unroll
            for (int ni = 0; ni < 4; ++ni) {
                int r = c0 + ni * 16 + l15;
                bfr[ni] = *(const bf16x8*)&Bs[cur][r * 64 + (((kk * 4 + quad) ^ (r & 7)) * 8)];
            }
#pragma unroll
            for (int mi = 0; mi < 4; ++mi)
#pragma unroll
                for (int ni = 0; ni < 4; ++ni)
                    acc[mi][ni] = __builtin_amdgcn_mfma_f32_16x16x32_bf16(af[mi], bfr[ni], acc[mi][ni], 0, 0, 0);
        }
    }
#pragma unroll
    for (int mi = 0; mi < 4; ++mi)
#pragma unroll
        for (int ni = 0; ni < 4; ++ni)
#pragma unroll
            for (int r = 0; r < 4; ++r) {
                int m = m0 + r0 + mi * 16 + quad * 4 + r;
                int n = n0 + c0 + ni * 16 + l15;
                float v = acc[mi][ni][r] + bias[n];
                dst[(size_t)(n >> 6) * T * HD + (size_t)m * HD + (n & 63)] = f2bf(v);
            }
}

// ---------------------------------------------------------------- proj GEMM (fp32 out)
__global__ __launch_bounds__(256, 2) void gemm_proj_kernel(
    const u16* __restrict__ A, const u16* __restrict__ W,
    const float* __restrict__ bias, float* __restrict__ out) {
    __shared__ __align__(16) u16 As[2][128 * 64];
    __shared__ __align__(16) u16 Bs[2][128 * 64];
    const int m0 = blockIdx.x * 128, n0 = blockIdx.y * 128;
    const int tid = threadIdx.x;
    const int wave = tid >> 6, lane = tid & 63, quad = lane >> 4, l15 = lane & 15;
    const int r0 = (wave >> 1) * 64, c0 = (wave & 1) * 64;
    int srow[4], sx[4], sdst[4];
#pragma unroll
    for (int i = 0; i < 4; ++i) {
        int p = i * 256 + wave * 64 + lane;
        srow[i] = p >> 3;
        sx[i] = (p & 7) ^ (srow[i] & 7);
        sdst[i] = (i * 256 + wave * 64) * 8;
    }
    f32x4 acc[4][4] = {};
#pragma unroll
    for (int i = 0; i < 4; ++i) {
        load_lds16(A + (size_t)(m0 + srow[i]) * C + sx[i] * 8, &As[0][sdst[i]]);
        load_lds16(W + (size_t)(n0 + srow[i]) * C + sx[i] * 8, &Bs[0][sdst[i]]);
    }
    for (int kt = 0; kt < 12; ++kt) {
        const int cur = kt & 1;
        __syncthreads();
        if (kt < 11) {
            const int k0 = (kt + 1) * 64;
#pragma unroll
            for (int i = 0; i < 4; ++i) {
                load_lds16(A + (size_t)(m0 + srow[i]) * C + k0 + sx[i] * 8, &As[cur ^ 1][sdst[i]]);
                load_lds16(W + (size_t)(n0 + srow[i]) * C + k0 + sx[i] * 8, &Bs[cur ^ 1][sdst[i]]);
            }
        }
#pragma unroll
        for (int kk = 0; kk < 2; ++kk) {
            bf16x8 af[4], bfr[4];
#pragma unroll
            for (int mi = 0; mi < 4; ++mi) {
                int r = r0 + mi * 16 + l15;
                af[mi] = *(const bf16x8*)&As[cur][r * 64 + (((kk * 4 + quad) ^ (r & 7)) * 8)];
            }
#pragma unroll
            for (int ni = 0; ni < 4; ++ni) {
                int r = c0 + ni * 16 + l15;
                bfr[ni] = *(const bf16x8*)&Bs[cur][r * 64 + (((kk * 4 + quad) ^ (r & 7)) * 8)];
            }
#pragma unroll
            for (int mi = 0; mi < 4; ++mi)
#pragma unroll
                for (int ni = 0; ni < 4; ++ni)
                    acc[mi][ni] = __builtin_amdgcn_mfma_f32_16x16x32_bf16(af[mi], bfr[ni], acc[mi][ni], 0, 0, 0);
        }
    }
#pragma unroll
    for (int mi = 0; mi < 4; ++mi)
#pragma unroll
        for (int ni = 0; ni < 4; ++ni)
#pragma unroll
            for (int r = 0; r < 4; ++r) {
                int m = m0 + r0 + mi * 16 + quad * 4 + r;
                int n = n0 + c0 + ni * 16 + l15;
                out[(size_t)m * C + n] = acc[mi][ni][r] + bias[n];
            }
}

// ---------------------------------------------------------------- V transpose
__global__ __launch_bounds__(256) void vtrans_kernel(const u16* __restrict__ V,
                                                     u16* __restrict__ Vt) {
    __shared__ __align__(16) u16 tl[64 * 72];
    const int h = blockIdx.y, t0 = blockIdx.x * 64, tid = threadIdx.x;
#pragma unroll
    for (int i = 0; i < 2; ++i) {
        int c = i * 256 + tid;
        int row = c >> 3, col = (c & 7) * 8;
        union { float4 f; u16 u[8]; } cv;
        cv.f = *(const float4*)(V + (size_t)h * T * HD + (size_t)(t0 + row) * HD + col);
#pragma unroll
        for (int j = 0; j < 8; ++j) tl[(col + j) * 72 + row] = cv.u[j];
    }
    __syncthreads();
#pragma unroll
    for (int i = 0; i < 2; ++i) {
        int c = i * 256 + tid;
        int drow = c >> 3, tcol = (c & 7) * 8;
        float4 v = *(const float4*)&tl[drow * 72 + tcol];
        *(float4*)(Vt + (size_t)(h * HD + drow) * T + t0 + tcol) = v;
    }
}

// ---------------------------------------------------------------- rel_h
// OUT: relH[h][hq][wq][hk] (hk contiguous), pre-scaled by log2e.
__global__ __launch_bounds__(256) void relh_kernel(const u16* __restrict__ Q,
                                                   const u16* __restrict__ rph,
                                                   float* __restrict__ relH) {
    const float LOG2E = 1.4426950408889634f;
    const int hq = blockIdx.x, h = blockIdx.y;
    const int tid = threadIdx.x, wave = tid >> 6, lane = tid & 63;
    const int quad = lane >> 4, l15 = lane & 15;
    f32x4 acc[4] = {};
    bf16x8 a[2], b[4][2];
#pragma unroll
    for (int kk = 0; kk < 2; ++kk) {
        int hk = wave * 16 + l15;
        a[kk] = *(const bf16x8*)(rph + (size_t)(hq - hk + 63) * HD + kk * 32 + quad * 8);
    }
#pragma unroll
    for (int nt = 0; nt < 4; ++nt)
#pragma unroll
        for (int kk = 0; kk < 2; ++kk)
            b[nt][kk] = *(const bf16x8*)(Q + (size_t)h * T * HD +
                                         (size_t)(hq * 64 + nt * 16 + l15) * HD + kk * 32 + quad * 8);
#pragma unroll
    for (int nt = 0; nt < 4; ++nt) {
        acc[nt] = __builtin_amdgcn_mfma_f32_16x16x32_bf16(a[0], b[nt][0], acc[nt], 0, 0, 0);
        acc[nt] = __builtin_amdgcn_mfma_f32_16x16x32_bf16(a[1], b[nt][1], acc[nt], 0, 0, 0);
    }
#pragma unroll
    for (int nt = 0; nt < 4; ++nt) {
        float4 v;
        v.x = acc[nt][0] * LOG2E; v.y = acc[nt][1] * LOG2E;
        v.z = acc[nt][2] * LOG2E; v.w = acc[nt][3] * LOG2E;
        *(float4*)(relH + (((size_t)(h * 64 + hq) * 64 + nt * 16 + l15) * 64) +
                   wave * 16 + quad * 4) = v;
    }
}

// ---------------------------------------------------------------- rel_w
// OUT: relW[h][t][wk] (wk contiguous), pre-scaled by log2e.
__global__ __launch_bounds__(256) void relw_kernel(const u16* __restrict__ Q,
                                                   const u16* __restrict__ rpw,
                                                   float* __restrict__ relW) {
    const float LOG2E = 1.4426950408889634f;
    const int wq = blockIdx.x, h = blockIdx.y;
    const int tid = threadIdx.x, wave = tid >> 6, lane = tid & 63;
    const int quad = lane >> 4, l15 = lane & 15;
    f32x4 acc[4] = {};
    bf16x8 a[2], b[4][2];
#pragma unroll
    for (int kk = 0; kk < 2; ++kk) {
        int hqr = wave * 16 + l15;
        a[kk] = *(const bf16x8*)(Q + (size_t)h * T * HD +
                                 (size_t)(hqr * 64 + wq) * HD + kk * 32 + quad * 8);
    }
#pragma unroll
    for (int nt = 0; nt < 4; ++nt)
#pragma unroll
        for (int kk = 0; kk < 2; ++kk) {
            int wk = nt * 16 + l15;
            b[nt][kk] = *(const bf16x8*)(rpw + (size_t)(wq - wk + 63) * HD + kk * 32 + quad * 8);
        }
#pragma unroll
    for (int nt = 0; nt < 4; ++nt) {
        acc[nt] = __builtin_amdgcn_mfma_f32_16x16x32_bf16(a[0], b[nt][0], acc[nt], 0, 0, 0);
        acc[nt] = __builtin_amdgcn_mfma_f32_16x16x32_bf16(a[1], b[nt][1], acc[nt], 0, 0, 0);
    }
#pragma unroll
    for (int nt = 0; nt < 4; ++nt)
#pragma unroll
        for (int r = 0; r < 4; ++r) {
            int hqr = wave * 16 + quad * 4 + r;
            relW[((size_t)h * T + hqr * 64 + wq) * 64 + nt * 16 + l15] = acc[nt][r] * LOG2E;
        }
}

// ---------------------------------------------------------------- flash attention (2x2 wave split)
// block = 64 q (one hq row); wave w: q-half qh=w>>1 (32 q), key-half kh=w&1 (32 keys).
// LDS reads/iter/wave: 4 b128 (K) + 8 b64 (V) — half of R7's q-split, with only
// ~115 live VGPRs (R8's key-split needed ~164 and spilled). No-max softmax =>
// partials over disjoint key-halves are additive; epilogue combines via LDS
// (reuses the K/V staging space).
__global__ __launch_bounds__(256, 3) void attn_kernel(
    const u16* __restrict__ Q, const u16* __restrict__ K, const u16* __restrict__ Vt,
    const float* __restrict__ relH, const float* __restrict__ relW,
    u16* __restrict__ AO) {
    // loop: kb [2][4096] u16 (0..16383) | vb [2][4096] u16 (16384..32767)
    // epilogue (reuse): fs f32[64][68] (0..17407) | rs f32[64] (17408..17663)
    __shared__ __align__(16) unsigned char smem[32768];
    u16* kb = (u16*)smem;
    u16* vb = (u16*)(smem + 16384);
    float* fs = (float*)smem;
    float* rs = (float*)(smem + 17408);

    const int hq = blockIdx.x, h = blockIdx.y;
    const int t0 = hq * 64;
    const int tid = threadIdx.x, w = tid >> 6, lane = tid & 63;
    const int quad = lane >> 4, l15 = lane & 15;
    const int qh = w >> 1, kh = w & 1;
    const float C1 = 0.18033688011112042f;   // 0.125 * log2(e)

    const u16* Kbase = K + (size_t)h * T * HD;
    const u16* Vbase = Vt + (size_t)h * HD * T;

    // staging geometry (512 x 16B chunks per tile; 2 per thread)
    const int p0 = w * 128 + lane, p1 = p0 + 64;
    const int sr0 = p0 >> 3, sx0 = (p0 & 7) ^ (sr0 & 7);
    const int sr1 = p1 >> 3, sx1 = (p1 & 7) ^ (sr1 & 7);
    const int lds0 = w * 1024, lds1 = w * 1024 + 512;

    // Q B-fragments: q = t0 + qh*32 + b*16 + l15
    bf16x8 qa[2][2];
#pragma unroll
    for (int b = 0; b < 2; ++b)
#pragma unroll
        for (int kk = 0; kk < 2; ++kk)
            qa[b][kk] = *(const bf16x8*)(Q + (size_t)h * T * HD +
                                         (size_t)(t0 + qh * 32 + b * 16 + l15) * HD + kk * 32 + quad * 8);
    // rel_w (pre-scaled): wk = kh*32 + ks*16 + quad*4 + r
    f32x4 rw4[2][2];
#pragma unroll
    for (int b = 0; b < 2; ++b)
#pragma unroll
        for (int ks = 0; ks < 2; ++ks)
            rw4[b][ks] = *(const f32x4*)(relW + ((size_t)h * T + t0 + qh * 32 + b * 16 + l15) * 64 +
                                         kh * 32 + ks * 16 + quad * 4);
    // rel_h (pre-scaled): [h][hq][q][hk], hk contiguous
    const float* rhB = relH + ((size_t)(h * 64 + hq) * 64 + qh * 32 + l15) * 64;

    f32x4 oa[2][4] = {};          // [qband][dg]
    float lsum[2] = {0.f, 0.f};

    // prologue: stage tile 0
    load_lds16(Kbase + sr0 * HD + sx0 * 8, &kb[lds0]);
    load_lds16(Kbase + sr1 * HD + sx1 * 8, &kb[lds1]);
    load_lds16(Vbase + (size_t)sr0 * T + sx0 * 8, &vb[lds0]);
    load_lds16(Vbase + (size_t)sr1 * T + sx1 * 8, &vb[lds1]);

    for (int hk4 = 0; hk4 < 16; ++hk4) {
        f32x4 rh4[2];
        rh4[0] = *(const f32x4*)(rhB + hk4 * 4);
        rh4[1] = *(const f32x4*)(rhB + 16 * 64 + hk4 * 4);
#pragma unroll
        for (int rr = 0; rr < 4; ++rr) {
            const int hk = hk4 * 4 + rr;
            const int cur = rr & 1;
            __syncthreads();
            if (hk < 63) {
                const int tk0 = (hk + 1) * 64;
                load_lds16(Kbase + (size_t)(tk0 + sr0) * HD + sx0 * 8, &kb[(cur ^ 1) * 4096 + lds0]);
                load_lds16(Kbase + (size_t)(tk0 + sr1) * HD + sx1 * 8, &kb[(cur ^ 1) * 4096 + lds1]);
                load_lds16(Vbase + (size_t)sr0 * T + tk0 + sx0 * 8, &vb[(cur ^ 1) * 4096 + lds0]);
                load_lds16(Vbase + (size_t)sr1 * T + tk0 + sx1 * 8, &vb[(cur ^ 1) * 4096 + lds1]);
            }
            const u16* kc = kb + cur * 4096;
            const u16* vc = vb + cur * 4096;
            // K A-fragments: keys kh*32 + ks*16 + l15 (4 x b128)
            bf16x8 af[2][2];
#pragma unroll
            for (int ks = 0; ks < 2; ++ks)
#pragma unroll
                for (int kk = 0; kk < 2; ++kk)
                    af[ks][kk] = *(const bf16x8*)&kc[(kh * 32 + ks * 16 + l15) * 64 +
                                                     (((kk * 4 + quad) ^ (l15 & 7)) * 8)];
            // V^T A-fragments: d = dg*16+l15, keys kh*32+ks*16+quad*4..+3 (8 x b64)
            s16x4 vf[4][2];
#pragma unroll
            for (int dg = 0; dg < 4; ++dg)
#pragma unroll
                for (int ks = 0; ks < 2; ++ks)
                    vf[dg][ks] = *(const s16x4*)&vc[(dg * 16 + l15) * 64 +
                                                    (((kh * 4 + ks * 2 + (quad >> 1)) ^ (l15 & 7)) * 8) +
                                                    (quad & 1) * 4];
#pragma unroll
            for (int b = 0; b < 2; ++b) {
                const float rhc = rh4[b][rr];
#pragma unroll
                for (int ks = 0; ks < 2; ++ks) {
                    f32x4 s4 = {};
                    s4 = __builtin_amdgcn_mfma_f32_16x16x32_bf16(af[ks][0], qa[b][0], s4, 0, 0, 0);
                    s4 = __builtin_amdgcn_mfma_f32_16x16x32_bf16(af[ks][1], qa[b][1], s4, 0, 0, 0);
                    float e0 = exp2_hw(s4[0] * C1 + rhc + rw4[b][ks][0]);
                    float e1 = exp2_hw(s4[1] * C1 + rhc + rw4[b][ks][1]);
                    float e2 = exp2_hw(s4[2] * C1 + rhc + rw4[b][ks][2]);
                    float e3 = exp2_hw(s4[3] * C1 + rhc + rw4[b][ks][3]);
                    lsum[b] += (e0 + e1) + (e2 + e3);
                    s16x4 pB;
                    pB[0] = (short)f2bf(e0); pB[1] = (short)f2bf(e1);
                    pB[2] = (short)f2bf(e2); pB[3] = (short)f2bf(e3);
#pragma unroll
                    for (int dg = 0; dg < 4; ++dg)
                        mfma16(oa[b][dg], vf[dg][ks], pB);
                }
            }
        }
    }
    // ---- combine across key-half waves (kh=1 publishes, kh=0 merges+stores) ----
    __syncthreads();                        // all loop LDS reads complete
#pragma unroll
    for (int b = 0; b < 2; ++b) {
        lsum[b] += __shfl_xor(lsum[b], 16);
        lsum[b] += __shfl_xor(lsum[b], 32); // sum over quads
    }
    if (kh == 1) {
        if (quad == 0) {
            rs[qh * 32 + l15] = lsum[0];
            rs[qh * 32 + 16 + l15] = lsum[1];
        }
#pragma unroll
        for (int b = 0; b < 2; ++b)
#pragma unroll
            for (int dg = 0; dg < 4; ++dg)
                *(f32x4*)&fs[(size_t)(qh * 32 + b * 16 + l15) * 68 + dg * 16 + quad * 4] = oa[b][dg];
    }
    __syncthreads();
    if (kh == 0) {
#pragma unroll
        for (int b = 0; b < 2; ++b) {
            const int q = qh * 32 + b * 16 + l15;
            const float inv = 1.0f / (lsum[b] + rs[q]);
#pragma unroll
            for (int dg = 0; dg < 4; ++dg) {
                f32x4 t4 = *(const f32x4*)&fs[(size_t)q * 68 + dg * 16 + quad * 4];
                float o0 = (oa[b][dg][0] + t4[0]) * inv;
                float o1 = (oa[b][dg][1] + t4[1]) * inv;
                float o2 = (oa[b][dg][2] + t4[2]) * inv;
                float o3 = (oa[b][dg][3] + t4[3]) * inv;
                uint2 st;
                st.x = (unsigned)f2bf(o0) | ((unsigned)f2bf(o1) << 16);
                st.y = (unsigned)f2bf(o2) | ((unsigned)f2bf(o3) << 16);
                *(uint2*)(AO + (size_t)(t0 + q) * C + h * 64 + dg * 16 + quad * 4) = st;
            }
        }
    }
}

// ---------------------------------------------------------------- launch
extern "C" void kernel_launch(void* const* d_in, const int* in_sizes, int n_in,
                              void* d_out, int out_size, void* d_ws, size_t ws_size,
                              hipStream_t stream) {
    (void)in_sizes; (void)n_in; (void)out_size; (void)ws_size;
    const float* hs  = (const float*)d_in[0];
    const float* q_w = (const float*)d_in[1];
    const float* q_b = (const float*)d_in[2];
    const float* k_w = (const float*)d_in[3];
    const float* k_b = (const float*)d_in[4];
    const float* v_w = (const float*)d_in[5];
    const float* v_b = (const float*)d_in[6];
    const float* p_w = (const float*)d_in[7];
    const float* p_b = (const float*)d_in[8];
    const float* rph = (const float*)d_in[9];
    const float* rpw = (const float*)d_in[10];

    char* ws = (char*)d_ws;
    size_t off = 0;
    auto alloc = [&](size_t bytes) {
        void* p = ws + off;
        off = (off + bytes + 255) & ~(size_t)255;
        return p;
    };
    u16* xb   = (u16*)alloc((size_t)T * C * 2);
    u16* wqb  = (u16*)alloc((size_t)C * C * 2);
    u16* wkb  = (u16*)alloc((size_t)C * C * 2);
    u16* wvb  = (u16*)alloc((size_t)C * C * 2);
    u16* wpb  = (u16*)alloc((size_t)C * C * 2);
    u16* rphb = (u16*)alloc((size_t)127 * HD * 2);
    u16* rpwb = (u16*)alloc((size_t)127 * HD * 2);
    u16* Qb   = (u16*)alloc((size_t)NH * T * HD * 2);
    u16* Kb   = (u16*)alloc((size_t)NH * T * HD * 2);
    u16* Vb   = (u16*)alloc((size_t)NH * T * HD * 2);
    u16* Vt   = (u16*)alloc((size_t)NH * T * HD * 2);
    float* relH = (float*)alloc((size_t)NH * T * 64 * 4);
    float* relW = (float*)alloc((size_t)NH * T * 64 * 4);
    u16* AO   = (u16*)alloc((size_t)T * C * 2);

    const int NTOT = T * C + 4 * C * C + 2 * 127 * HD;
    cvt_all<<<dim3((NTOT / 4 + 255) / 256), dim3(256), 0, stream>>>(
        hs, q_w, k_w, v_w, p_w, rph, rpw, xb, wqb, wkb, wvb, wpb, rphb, rpwb);

    gemm_qkv_kernel<<<dim3(32, 6, 3), dim3(256), 0, stream>>>(
        xb, wqb, wkb, wvb, q_b, k_b, v_b, Qb, Kb, Vb);
    vtrans_kernel<<<dim3(64, NH), dim3(256), 0, stream>>>(Vb, Vt);
    relh_kernel<<<dim3(64, NH), dim3(256), 0, stream>>>(Qb, rphb, relH);
    relw_kernel<<<dim3(64, NH), dim3(256), 0, stream>>>(Qb, rpwb, relW);
    attn_kernel<<<dim3(64, NH), dim3(256), 0, stream>>>(Qb, Kb, Vt, relH, relW, AO);
    gemm_proj_kernel<<<dim3(32, 6), dim3(256), 0, stream>>>(AO, wpb, p_b, (float*)d_out);
}

// Round 10
// 222.927 us; speedup vs baseline: 2.3237x; 1.0494x over previous
//
#include <hip/hip_runtime.h>
#include <cstdint>
#include <cstddef>

#define T 4096
#define C 768
#define HD 64
#define NH 12

typedef float f32x4 __attribute__((ext_vector_type(4)));
typedef __bf16 bf16x8 __attribute__((ext_vector_type(8)));
typedef short s16x4 __attribute__((ext_vector_type(4)));
typedef unsigned short u16;

static __device__ __forceinline__ u16 f2bf(float f) {
    union { __bf16 h; u16 u; } cv;
    cv.h = (__bf16)f;
    return cv.u;
}

static __device__ __forceinline__ float exp2_hw(float x) {
    float r;
    asm("v_exp_f32 %0, %1" : "=v"(r) : "v"(x));
    return r;
}

static __device__ __forceinline__ void load_lds16(const void* g, void* l) {
    __builtin_amdgcn_global_load_lds(
        (const __attribute__((address_space(1))) void*)g,
        (__attribute__((address_space(3))) void*)l, 16, 0, 0);
}

// D = A(16x16)*B(16x16)+D, bf16 K=16; A/B: 4 bf16/lane, k = quad*4 + j.
static __device__ __forceinline__ void mfma16(f32x4& acc, s16x4 a, s16x4 b) {
#if defined(__HIP_DEVICE_COMPILE__)
#if __has_builtin(__builtin_amdgcn_mfma_f32_16x16x16bf16_1k)
    acc = __builtin_amdgcn_mfma_f32_16x16x16bf16_1k(a, b, acc, 0, 0, 0);
#else
    asm volatile("s_nop 2\n\t"
                 "v_mfma_f32_16x16x16_bf16 %0, %1, %2, %0\n\t"
                 "s_nop 7\n\t"
                 "s_nop 7"
                 : "+v"(acc) : "v"(a), "v"(b));
#endif
#else
    (void)acc; (void)a; (void)b;
#endif
}

// ---------------------------------------------------------------- convert (all inputs, one launch)
__global__ __launch_bounds__(256) void cvt_all(
    const float* __restrict__ hs, const float* __restrict__ w0,
    const float* __restrict__ w1, const float* __restrict__ w2,
    const float* __restrict__ w3, const float* __restrict__ rh,
    const float* __restrict__ rw,
    u16* __restrict__ dhs, u16* __restrict__ dw0, u16* __restrict__ dw1,
    u16* __restrict__ dw2, u16* __restrict__ dw3, u16* __restrict__ drh,
    u16* __restrict__ drw) {
    const int NHS = T * C;
    const int NW = C * C;
    const int NR = 127 * HD;
    const int NTOT = NHS + 4 * NW + 2 * NR;
    int i = (blockIdx.x * 256 + threadIdx.x) * 4;
    if (i >= NTOT) return;
    const float* s; u16* d; int j;
    if (i < NHS) { s = hs; d = dhs; j = i; }
    else if (i < NHS + 4 * NW) {
        j = i - NHS;
        int t = j / NW; j -= t * NW;
        s = (t == 0) ? w0 : (t == 1) ? w1 : (t == 2) ? w2 : w3;
        d = (t == 0) ? dw0 : (t == 1) ? dw1 : (t == 2) ? dw2 : dw3;
    } else {
        j = i - NHS - 4 * NW;
        if (j < NR) { s = rh; d = drh; }
        else { s = rw; d = drw; j -= NR; }
    }
    float4 v = *(const float4*)(s + j);
    d[j + 0] = f2bf(v.x);
    d[j + 1] = f2bf(v.y);
    d[j + 2] = f2bf(v.z);
    d[j + 3] = f2bf(v.w);
}

// ---------------------------------------------------------------- QKV GEMM
// z==2 (V) writes DIRECTLY transposed into Vt[n*T + m] (vtrans kernel deleted):
// with HD=64, (h*HD + d)*T + t == n*T + m. 4 consecutive m per lane -> uint2.
__global__ __launch_bounds__(256, 2) void gemm_qkv_kernel(
    const u16* __restrict__ xb,
    const u16* __restrict__ wq, const u16* __restrict__ wk, const u16* __restrict__ wv,
    const float* __restrict__ qb, const float* __restrict__ kb, const float* __restrict__ vb,
    u16* __restrict__ Q, u16* __restrict__ K, u16* __restrict__ Vt) {
    __shared__ __align__(16) u16 As[2][128 * 64];
    __shared__ __align__(16) u16 Bs[2][128 * 64];
    const int z = blockIdx.z;
    const u16* W = (z == 0) ? wq : (z == 1) ? wk : wv;
    const float* bias = (z == 0) ? qb : (z == 1) ? kb : vb;
    u16* dst = (z == 0) ? Q : (z == 1) ? K : Vt;
    const int m0 = blockIdx.x * 128, n0 = blockIdx.y * 128;
    const int tid = threadIdx.x;
    const int wave = tid >> 6, lane = tid & 63, quad = lane >> 4, l15 = lane & 15;
    const int r0 = (wave >> 1) * 64, c0 = (wave & 1) * 64;
    int srow[4], sx[4], sdst[4];
#pragma unroll
    for (int i = 0; i < 4; ++i) {
        int p = i * 256 + wave * 64 + lane;
        srow[i] = p >> 3;
        sx[i] = (p & 7) ^ (srow[i] & 7);
        sdst[i] = (i * 256 + wave * 64) * 8;
    }
    f32x4 acc[4][4] = {};
#pragma unroll
    for (int i = 0; i < 4; ++i) {
        load_lds16(xb + (size_t)(m0 + srow[i]) * C + sx[i] * 8, &As[0][sdst[i]]);
        load_lds16(W + (size_t)(n0 + srow[i]) * C + sx[i] * 8, &Bs[0][sdst[i]]);
    }
    for (int kt = 0; kt < 12; ++kt) {
        const int cur = kt & 1;
        __syncthreads();
        if (kt < 11) {
            const int k0 = (kt + 1) * 64;
#pragma unroll
            for (int i = 0; i < 4; ++i) {
                load_lds16(xb + (size_t)(m0 + srow[i]) * C + k0 + sx[i] * 8, &As[cur ^ 1][sdst[i]]);
                load_lds16(W + (size_t)(n0 + srow[i]) * C + k0 + sx[i] * 8, &Bs[cur ^ 1][sdst[i]]);
            }
        }
#pragma unroll
        for (int kk = 0; kk < 2; ++kk) {
            bf16x8 af[4], bfr[4];
#pragma unroll
            for (int mi = 0; mi < 4; ++mi) {
                int r = r0 + mi * 16 + l15;
                af[mi] = *(const bf16x8*)&As[cur][r * 64 + (((kk * 4 + quad) ^ (r & 7)) * 8)];
            }
#pragma unroll
            for (int ni = 0; ni < 4; ++ni) {
                int r = c0 + ni * 16 + l15;
                bfr[ni] = *(const bf16x8*)&Bs[cur][r * 64 + (((kk * 4 + quad) ^ (r & 7)) * 8)];
            }
#pragma unroll
            for (int mi = 0; mi < 4; ++mi)
#pragma unroll
                for (int ni = 0; ni < 4; ++ni)
                    acc[mi][ni] = __builtin_amdgcn_mfma_f32_16x16x32_bf16(af[mi], bfr[ni], acc[mi][ni], 0, 0, 0);
        }
    }
    if (z == 2) {
#pragma unroll
        for (int mi = 0; mi < 4; ++mi)
#pragma unroll
            for (int ni = 0; ni < 4; ++ni) {
                int m = m0 + r0 + mi * 16 + quad * 4;
                int n = n0 + c0 + ni * 16 + l15;
                float b = bias[n];
                uint2 st;
                st.x = (unsigned)f2bf(acc[mi][ni][0] + b) |
                       ((unsigned)f2bf(acc[mi][ni][1] + b) << 16);
                st.y = (unsigned)f2bf(acc[mi][ni][2] + b) |
                       ((unsigned)f2bf(acc[mi][ni][3] + b) << 16);
                *(uint2*)(dst + (size_t)n * T + m) = st;
            }
    } else {
#pragma unroll
        for (int mi = 0; mi < 4; ++mi)
#pragma unroll
            for (int ni = 0; ni < 4; ++ni)
#pragma unroll
                for (int r = 0; r < 4; ++r) {
                    int m = m0 + r0 + mi * 16 + quad * 4 + r;
                    int n = n0 + c0 + ni * 16 + l15;
                    float v = acc[mi][ni][r] + bias[n];
                    dst[(size_t)(n >> 6) * T * HD + (size_t)m * HD + (n & 63)] = f2bf(v);
                }
    }
}

// ---------------------------------------------------------------- proj GEMM (128x64 tiles, 384 blocks)
__global__ __launch_bounds__(256, 2) void gemm_proj_kernel(
    const u16* __restrict__ A, const u16* __restrict__ W,
    const float* __restrict__ bias, float* __restrict__ out) {
    __shared__ __align__(16) u16 As[2][128 * 64];
    __shared__ __align__(16) u16 Bs[2][64 * 64];
    const int m0 = blockIdx.x * 128, n0 = blockIdx.y * 64;
    const int tid = threadIdx.x;
    const int wave = tid >> 6, lane = tid & 63, quad = lane >> 4, l15 = lane & 15;
    const int r0 = (wave >> 1) * 64, c0 = (wave & 1) * 32;
    int srA[4], sxA[4], sdA[4], srB[2], sxB[2], sdB[2];
#pragma unroll
    for (int i = 0; i < 4; ++i) {
        int p = i * 256 + wave * 64 + lane;
        srA[i] = p >> 3; sxA[i] = (p & 7) ^ (srA[i] & 7);
        sdA[i] = (i * 256 + wave * 64) * 8;
    }
#pragma unroll
    for (int i = 0; i < 2; ++i) {
        int p = i * 256 + wave * 64 + lane;
        srB[i] = p >> 3; sxB[i] = (p & 7) ^ (srB[i] & 7);
        sdB[i] = (i * 256 + wave * 64) * 8;
    }
    f32x4 acc[4][2] = {};
#pragma unroll
    for (int i = 0; i < 4; ++i)
        load_lds16(A + (size_t)(m0 + srA[i]) * C + sxA[i] * 8, &As[0][sdA[i]]);
#pragma unroll
    for (int i = 0; i < 2; ++i)
        load_lds16(W + (size_t)(n0 + srB[i]) * C + sxB[i] * 8, &Bs[0][sdB[i]]);
    for (int kt = 0; kt < 12; ++kt) {
        const int cur = kt & 1;
        __syncthreads();
        if (kt < 11) {
            const int k0 = (kt + 1) * 64;
#pragma unroll
            for (int i = 0; i < 4; ++i)
                load_lds16(A + (size_t)(m0 + srA[i]) * C + k0 + sxA[i] * 8, &As[cur ^ 1][sdA[i]]);
#pragma unroll
            for (int i = 0; i < 2; ++i)
                load_lds16(W + (size_t)(n0 + srB[i]) * C + k0 + sxB[i] * 8, &Bs[cur ^ 1][sdB[i]]);
        }
#pragma unroll
        for (int kk = 0; kk < 2; ++kk) {
            bf16x8 af[4], bfr[2];
#pragma unroll
            for (int mi = 0; mi < 4; ++mi) {
                int r = r0 + mi * 16 + l15;
                af[mi] = *(const bf16x8*)&As[cur][r * 64 + (((kk * 4 + quad) ^ (r & 7)) * 8)];
            }
#pragma unroll
            for (int ni = 0; ni < 2; ++ni) {
                int r = c0 + ni * 16 + l15;
                bfr[ni] = *(const bf16x8*)&Bs[cur][r * 64 + (((kk * 4 + quad) ^ (r & 7)) * 8)];
            }
#pragma unroll
            for (int mi = 0; mi < 4; ++mi)
#pragma unroll
                for (int ni = 0; ni < 2; ++ni)
                    acc[mi][ni] = __builtin_amdgcn_mfma_f32_16x16x32_bf16(af[mi], bfr[ni], acc[mi][ni], 0, 0, 0);
        }
    }
#pragma unroll
    for (int mi = 0; mi < 4; ++mi)
#pragma unroll
        for (int ni = 0; ni < 2; ++ni)
#pragma unroll
            for (int r = 0; r < 4; ++r) {
                int m = m0 + r0 + mi * 16 + quad * 4 + r;
                int n = n0 + c0 + ni * 16 + l15;
                out[(size_t)m * C + n] = acc[mi][ni][r] + bias[n];
            }
}

// ---------------------------------------------------------------- rel_h + rel_w (one launch, z branch)
// z=0: relH[h][hq][wq][hk] (hk contiguous); z=1: relW[h][t][wk] (wk contiguous).
// Both pre-scaled by log2e.
__global__ __launch_bounds__(256) void relhw_kernel(const u16* __restrict__ Q,
                                                    const u16* __restrict__ rph,
                                                    const u16* __restrict__ rpw,
                                                    float* __restrict__ relH,
                                                    float* __restrict__ relW) {
    const float LOG2E = 1.4426950408889634f;
    const int h = blockIdx.y;
    const int tid = threadIdx.x, wave = tid >> 6, lane = tid & 63;
    const int quad = lane >> 4, l15 = lane & 15;
    f32x4 acc[4] = {};
    bf16x8 a[2], b[4][2];
    if (blockIdx.z == 0) {
        const int hq = blockIdx.x;
#pragma unroll
        for (int kk = 0; kk < 2; ++kk) {
            int hk = wave * 16 + l15;                      // A: m = hk
            a[kk] = *(const bf16x8*)(rph + (size_t)(hq - hk + 63) * HD + kk * 32 + quad * 8);
        }
#pragma unroll
        for (int nt = 0; nt < 4; ++nt)
#pragma unroll
            for (int kk = 0; kk < 2; ++kk)                 // B: n = wq
                b[nt][kk] = *(const bf16x8*)(Q + (size_t)h * T * HD +
                                             (size_t)(hq * 64 + nt * 16 + l15) * HD + kk * 32 + quad * 8);
#pragma unroll
        for (int nt = 0; nt < 4; ++nt) {
            acc[nt] = __builtin_amdgcn_mfma_f32_16x16x32_bf16(a[0], b[nt][0], acc[nt], 0, 0, 0);
            acc[nt] = __builtin_amdgcn_mfma_f32_16x16x32_bf16(a[1], b[nt][1], acc[nt], 0, 0, 0);
        }
#pragma unroll
        for (int nt = 0; nt < 4; ++nt) {
            float4 v;
            v.x = acc[nt][0] * LOG2E; v.y = acc[nt][1] * LOG2E;
            v.z = acc[nt][2] * LOG2E; v.w = acc[nt][3] * LOG2E;
            *(float4*)(relH + (((size_t)(h * 64 + hq) * 64 + nt * 16 + l15) * 64) +
                       wave * 16 + quad * 4) = v;
        }
    } else {
        const int wq = blockIdx.x;
#pragma unroll
        for (int kk = 0; kk < 2; ++kk) {
            int hqr = wave * 16 + l15;                     // A: m = hq
            a[kk] = *(const bf16x8*)(Q + (size_t)h * T * HD +
                                     (size_t)(hqr * 64 + wq) * HD + kk * 32 + quad * 8);
        }
#pragma unroll
        for (int nt = 0; nt < 4; ++nt)
#pragma unroll
            for (int kk = 0; kk < 2; ++kk) {
                int wk = nt * 16 + l15;                    // B: n = wk
                b[nt][kk] = *(const bf16x8*)(rpw + (size_t)(wq - wk + 63) * HD + kk * 32 + quad * 8);
            }
#pragma unroll
        for (int nt = 0; nt < 4; ++nt) {
            acc[nt] = __builtin_amdgcn_mfma_f32_16x16x32_bf16(a[0], b[nt][0], acc[nt], 0, 0, 0);
            acc[nt] = __builtin_amdgcn_mfma_f32_16x16x32_bf16(a[1], b[nt][1], acc[nt], 0, 0, 0);
        }
#pragma unroll
        for (int nt = 0; nt < 4; ++nt)
#pragma unroll
            for (int r = 0; r < 4; ++r) {
                int hqr = wave * 16 + quad * 4 + r;
                relW[((size_t)h * T + hqr * 64 + wq) * 64 + nt * 16 + l15] = acc[nt][r] * LOG2E;
            }
    }
}

// ---------------------------------------------------------------- flash attention (2x2 wave split)
// block = 64 q; wave w: q-half qh=w>>1 (32 q), key-half kh=w&1 (32 keys).
// Rowsums via ones-MFMA (matrix pipe, rounded-P-consistent), not VALU adds.
__global__ __launch_bounds__(256, 3) void attn_kernel(
    const u16* __restrict__ Q, const u16* __restrict__ K, const u16* __restrict__ Vt,
    const float* __restrict__ relH, const float* __restrict__ relW,
    u16* __restrict__ AO) {
    // loop: kb [2][4096] u16 (0..16383) | vb [2][4096] u16 (16384..32767)
    // epilogue (reuse): fs f32[64][68] (0..17407) | rs f32[64] (17408..17663)
    __shared__ __align__(16) unsigned char smem[32768];
    u16* kb = (u16*)smem;
    u16* vb = (u16*)(smem + 16384);
    float* fs = (float*)smem;
    float* rs = (float*)(smem + 17408);

    const int hq = blockIdx.x, h = blockIdx.y;
    const int t0 = hq * 64;
    const int tid = threadIdx.x, w = tid >> 6, lane = tid & 63;
    const int quad = lane >> 4, l15 = lane & 15;
    const int qh = w >> 1, kh = w & 1;
    const float C1 = 0.18033688011112042f;   // 0.125 * log2(e)

    const u16* Kbase = K + (size_t)h * T * HD;
    const u16* Vbase = Vt + (size_t)h * HD * T;

    const int p0 = w * 128 + lane, p1 = p0 + 64;
    const int sr0 = p0 >> 3, sx0 = (p0 & 7) ^ (sr0 & 7);
    const int sr1 = p1 >> 3, sx1 = (p1 & 7) ^ (sr1 & 7);
    const int lds0 = w * 1024, lds1 = w * 1024 + 512;

    bf16x8 qa[2][2];
#pragma unroll
    for (int b = 0; b < 2; ++b)
#pragma unroll
        for (int kk = 0; kk < 2; ++kk)
            qa[b][kk] = *(const bf16x8*)(Q + (size_t)h * T * HD +
                                         (size_t)(t0 + qh * 32 + b * 16 + l15) * HD + kk * 32 + quad * 8);
    f32x4 rw4[2][2];
#pragma unroll
    for (int b = 0; b < 2; ++b)
#pragma unroll
        for (int ks = 0; ks < 2; ++ks)
            rw4[b][ks] = *(const f32x4*)(relW + ((size_t)h * T + t0 + qh * 32 + b * 16 + l15) * 64 +
                                         kh * 32 + ks * 16 + quad * 4);
    const float* rhB = relH + ((size_t)(h * 64 + hq) * 64 + qh * 32 + l15) * 64;

    s16x4 ones;
#pragma unroll
    for (int j = 0; j < 4; ++j) ones[j] = (short)0x3F80;

    f32x4 oa[2][4] = {};          // [qband][dg]
    f32x4 lacc[2] = {};           // rowsum via ones-MFMA (rows replicated)

    load_lds16(Kbase + sr0 * HD + sx0 * 8, &kb[lds0]);
    load_lds16(Kbase + sr1 * HD + sx1 * 8, &kb[lds1]);
    load_lds16(Vbase + (size_t)sr0 * T + sx0 * 8, &vb[lds0]);
    load_lds16(Vbase + (size_t)sr1 * T + sx1 * 8, &vb[lds1]);

    for (int hk4 = 0; hk4 < 16; ++hk4) {
        f32x4 rh4[2];
        rh4[0] = *(const f32x4*)(rhB + hk4 * 4);
        rh4[1] = *(const f32x4*)(rhB + 16 * 64 + hk4 * 4);
#pragma unroll
        for (int rr = 0; rr < 4; ++rr) {
            const int hk = hk4 * 4 + rr;
            const int cur = rr & 1;
            __syncthreads();
            if (hk < 63) {
                const int tk0 = (hk + 1) * 64;
                load_lds16(Kbase + (size_t)(tk0 + sr0) * HD + sx0 * 8, &kb[(cur ^ 1) * 4096 + lds0]);
                load_lds16(Kbase + (size_t)(tk0 + sr1) * HD + sx1 * 8, &kb[(cur ^ 1) * 4096 + lds1]);
                load_lds16(Vbase + (size_t)sr0 * T + tk0 + sx0 * 8, &vb[(cur ^ 1) * 4096 + lds0]);
                load_lds16(Vbase + (size_t)sr1 * T + tk0 + sx1 * 8, &vb[(cur ^ 1) * 4096 + lds1]);
            }
            const u16* kc = kb + cur * 4096;
            const u16* vc = vb + cur * 4096;
            bf16x8 af[2][2];
#pragma unroll
            for (int ks = 0; ks < 2; ++ks)
#pragma unroll
                for (int kk = 0; kk < 2; ++kk)
                    af[ks][kk] = *(const bf16x8*)&kc[(kh * 32 + ks * 16 + l15) * 64 +
                                                     (((kk * 4 + quad) ^ (l15 & 7)) * 8)];
            s16x4 vf[4][2];
#pragma unroll
            for (int dg = 0; dg < 4; ++dg)
#pragma unroll
                for (int ks = 0; ks < 2; ++ks)
                    vf[dg][ks] = *(const s16x4*)&vc[(dg * 16 + l15) * 64 +
                                                    (((kh * 4 + ks * 2 + (quad >> 1)) ^ (l15 & 7)) * 8) +
                                                    (quad & 1) * 4];
#pragma unroll
            for (int b = 0; b < 2; ++b) {
                const float rhc = rh4[b][rr];
#pragma unroll
                for (int ks = 0; ks < 2; ++ks) {
                    f32x4 s4 = {};
                    s4 = __builtin_amdgcn_mfma_f32_16x16x32_bf16(af[ks][0], qa[b][0], s4, 0, 0, 0);
                    s4 = __builtin_amdgcn_mfma_f32_16x16x32_bf16(af[ks][1], qa[b][1], s4, 0, 0, 0);
                    float e0 = exp2_hw(s4[0] * C1 + rhc + rw4[b][ks][0]);
                    float e1 = exp2_hw(s4[1] * C1 + rhc + rw4[b][ks][1]);
                    float e2 = exp2_hw(s4[2] * C1 + rhc + rw4[b][ks][2]);
                    float e3 = exp2_hw(s4[3] * C1 + rhc + rw4[b][ks][3]);
                    s16x4 pB;
                    pB[0] = (short)f2bf(e0); pB[1] = (short)f2bf(e1);
                    pB[2] = (short)f2bf(e2); pB[3] = (short)f2bf(e3);
                    mfma16(lacc[b], ones, pB);
#pragma unroll
                    for (int dg = 0; dg < 4; ++dg)
                        mfma16(oa[b][dg], vf[dg][ks], pB);
                }
            }
        }
    }
    // ---- combine across key-half waves (kh=1 publishes, kh=0 merges+stores) ----
    __syncthreads();                        // all loop LDS reads complete
    // lacc[b][0]: rowsum of this wave's 32 keys for q = qh*32+b*16+l15 (rows replicated)
    if (kh == 1) {
        if (quad == 0) {
            rs[qh * 32 + l15] = lacc[0][0];
            rs[qh * 32 + 16 + l15] = lacc[1][0];
        }
#pragma unroll
        for (int b = 0; b < 2; ++b)
#pragma unroll
            for (int dg = 0; dg < 4; ++dg)
                *(f32x4*)&fs[(size_t)(qh * 32 + b * 16 + l15) * 68 + dg * 16 + quad * 4] = oa[b][dg];
    }
    __syncthreads();
    if (kh == 0) {
#pragma unroll
        for (int b = 0; b < 2; ++b) {
            const int q = qh * 32 + b * 16 + l15;
            const float inv = 1.0f / (lacc[b][0] + rs[q]);
#pragma unroll
            for (int dg = 0; dg < 4; ++dg) {
                f32x4 t4 = *(const f32x4*)&fs[(size_t)q * 68 + dg * 16 + quad * 4];
                float o0 = (oa[b][dg][0] + t4[0]) * inv;
                float o1 = (oa[b][dg][1] + t4[1]) * inv;
                float o2 = (oa[b][dg][2] + t4[2]) * inv;
                float o3 = (oa[b][dg][3] + t4[3]) * inv;
                uint2 st;
                st.x = (unsigned)f2bf(o0) | ((unsigned)f2bf(o1) << 16);
                st.y = (unsigned)f2bf(o2) | ((unsigned)f2bf(o3) << 16);
                *(uint2*)(AO + (size_t)(t0 + q) * C + h * 64 + dg * 16 + quad * 4) = st;
            }
        }
    }
}

// ---------------------------------------------------------------- launch
extern "C" void kernel_launch(void* const* d_in, const int* in_sizes, int n_in,
                              void* d_out, int out_size, void* d_ws, size_t ws_size,
                              hipStream_t stream) {
    (void)in_sizes; (void)n_in; (void)out_size; (void)ws_size;
    const float* hs  = (const float*)d_in[0];
    const float* q_w = (const float*)d_in[1];
    const float* q_b = (const float*)d_in[2];
    const float* k_w = (const float*)d_in[3];
    const float* k_b = (const float*)d_in[4];
    const float* v_w = (const float*)d_in[5];
    const float* v_b = (const float*)d_in[6];
    const float* p_w = (const float*)d_in[7];
    const float* p_b = (const float*)d_in[8];
    const float* rph = (const float*)d_in[9];
    const float* rpw = (const float*)d_in[10];

    char* ws = (char*)d_ws;
    size_t off = 0;
    auto alloc = [&](size_t bytes) {
        void* p = ws + off;
        off = (off + bytes + 255) & ~(size_t)255;
        return p;
    };
    u16* xb   = (u16*)alloc((size_t)T * C * 2);
    u16* wqb  = (u16*)alloc((size_t)C * C * 2);
    u16* wkb  = (u16*)alloc((size_t)C * C * 2);
    u16* wvb  = (u16*)alloc((size_t)C * C * 2);
    u16* wpb  = (u16*)alloc((size_t)C * C * 2);
    u16* rphb = (u16*)alloc((size_t)127 * HD * 2);
    u16* rpwb = (u16*)alloc((size_t)127 * HD * 2);
    u16* Qb   = (u16*)alloc((size_t)NH * T * HD * 2);
    u16* Kb   = (u16*)alloc((size_t)NH * T * HD * 2);
    u16* Vt   = (u16*)alloc((size_t)NH * T * HD * 2);
    float* relH = (float*)alloc((size_t)NH * T * 64 * 4);
    float* relW = (float*)alloc((size_t)NH * T * 64 * 4);
    u16* AO   = (u16*)alloc((size_t)T * C * 2);

    const int NTOT = T * C + 4 * C * C + 2 * 127 * HD;
    cvt_all<<<dim3((NTOT / 4 + 255) / 256), dim3(256), 0, stream>>>(
        hs, q_w, k_w, v_w, p_w, rph, rpw, xb, wqb, wkb, wvb, wpb, rphb, rpwb);

    gemm_qkv_kernel<<<dim3(32, 6, 3), dim3(256), 0, stream>>>(
        xb, wqb, wkb, wvb, q_b, k_b, v_b, Qb, Kb, Vt);
    relhw_kernel<<<dim3(64, NH, 2), dim3(256), 0, stream>>>(Qb, rphb, rpwb, relH, relW);
    attn_kernel<<<dim3(64, NH), dim3(256), 0, stream>>>(Qb, Kb, Vt, relH, relW, AO);
    gemm_proj_kernel<<<dim3(32, 12), dim3(256), 0, stream>>>(AO, wpb, p_b, (float*)d_out);
}